// Round 1
// baseline (577.139 us; speedup 1.0000x reference)
//
#include <hip/hip_runtime.h>

// Problem constants (fixed by reference)
constexpr int V_    = 2562;
constexpr int DEG_  = 8;
constexpr int FIN_  = 8;
constexpr int FOUT_ = 16;
constexpr int S_    = 512;            // X*Y*Z
constexpr int D_    = FIN_ * S_;      // 4096 floats per vertex row
constexpr int VS_   = V_ * S_;        // stride between f-planes

__device__ __forceinline__ float4 ld4(const float* p) {
    return *reinterpret_cast<const float4*>(p);
}
__device__ __forceinline__ void st4(float* p, float4 v) {
    *reinterpret_cast<float4*>(p) = v;
}

// One Chebyshev step fused with its output contribution.
//   x_k[f,v,s] = (FIRST ? 1 : 2) * sum_j vals[v,j]*prev[f,cols[v,j],s]  (- pprev[f,v,s] if !FIRST)
//   out[o,v,s] (+)= sum_f W[KIDX,f,o]*x_k[f,v,s]   (FIRST also adds bias + W[0]·x0)
// Block = one vertex. 256 threads. LDS tile holds the 4096-float x_k row.
template<int KIDX, bool FIRST, bool STORE>
__global__ __launch_bounds__(256)
void cheb_step(const float* __restrict__ x0,     // inputs, [FIN,V,S] view
               const float* __restrict__ prev,   // x_{k-1}
               const float* __restrict__ pprev,  // x_{k-2} (elementwise only)
               float*       __restrict__ dst,    // x_k (written iff STORE)
               const int*   __restrict__ cols,
               const float* __restrict__ vals,
               const float* __restrict__ W,      // [K,FIN,FOUT]
               const float* __restrict__ bias,   // [FOUT]
               float*       __restrict__ out)    // [FOUT,V,S]
{
    __shared__ float xk[D_];                     // 16 KB
    const int v = blockIdx.x;
    const int t = threadIdx.x;

    // block-uniform neighbor list -> scalar loads
    int   nb[DEG_];
    float wv[DEG_];
#pragma unroll
    for (int j = 0; j < DEG_; ++j) {
        nb[j] = cols[v * DEG_ + j] * S_;
        wv[j] = vals[v * DEG_ + j];
    }

    // ---- phase 1: compute x_k row v (4 float4 chunks per thread) ----
#pragma unroll
    for (int i = 0; i < 4; ++i) {
        const int c    = i * 256 + t;            // float4 chunk in [0,1024)
        const int f    = c >> 7;                 // feature plane
        const int soff = (c & 127) << 2;         // s offset (floats)
        const int fbase = f * VS_ + soff;
        float ax = 0.f, ay = 0.f, az = 0.f, aw = 0.f;
#pragma unroll
        for (int j = 0; j < DEG_; ++j) {
            const float4 p = ld4(prev + fbase + nb[j]);
            const float  w = wv[j];
            ax = fmaf(w, p.x, ax);
            ay = fmaf(w, p.y, ay);
            az = fmaf(w, p.z, az);
            aw = fmaf(w, p.w, aw);
        }
        if (!FIRST) {
            const float4 pp = ld4(pprev + fbase + v * S_);
            ax = 2.f * ax - pp.x;
            ay = 2.f * ay - pp.y;
            az = 2.f * az - pp.z;
            aw = 2.f * aw - pp.w;
        }
        const float4 r = make_float4(ax, ay, az, aw);
        if (STORE) st4(dst + fbase + v * S_, r);
        st4(&xk[c << 2], r);
    }
    __syncthreads();

    // ---- phase 2: out contribution. t<128 -> o 0..7, t>=128 -> o 8..15 ----
    const int soff  = (t & 127) << 2;
    const int obase = (t >> 7) * 8;

    float4 xf[FIN_];
#pragma unroll
    for (int f = 0; f < FIN_; ++f) xf[f] = ld4(&xk[f * S_ + soff]);

    float4 x0f[FIN_];
    if (FIRST) {
#pragma unroll
        for (int f = 0; f < FIN_; ++f) x0f[f] = ld4(x0 + f * VS_ + v * S_ + soff);
    }

#pragma unroll
    for (int oo = 0; oo < 8; ++oo) {
        const int o = obase + oo;
        float* op = out + o * VS_ + v * S_ + soff;
        float4 acc;
        if (FIRST) {
            const float b = bias[o];
            acc = make_float4(b, b, b, b);
#pragma unroll
            for (int f = 0; f < FIN_; ++f) {
                const float w0 = W[(0 * FIN_ + f) * FOUT_ + o];
                const float w1 = W[(1 * FIN_ + f) * FOUT_ + o];
                acc.x = fmaf(w0, x0f[f].x, acc.x);
                acc.y = fmaf(w0, x0f[f].y, acc.y);
                acc.z = fmaf(w0, x0f[f].z, acc.z);
                acc.w = fmaf(w0, x0f[f].w, acc.w);
                acc.x = fmaf(w1, xf[f].x, acc.x);
                acc.y = fmaf(w1, xf[f].y, acc.y);
                acc.z = fmaf(w1, xf[f].z, acc.z);
                acc.w = fmaf(w1, xf[f].w, acc.w);
            }
        } else {
            acc = ld4(op);
#pragma unroll
            for (int f = 0; f < FIN_; ++f) {
                const float wk = W[(KIDX * FIN_ + f) * FOUT_ + o];
                acc.x = fmaf(wk, xf[f].x, acc.x);
                acc.y = fmaf(wk, xf[f].y, acc.y);
                acc.z = fmaf(wk, xf[f].z, acc.z);
                acc.w = fmaf(wk, xf[f].w, acc.w);
            }
        }
        st4(op, acc);
    }
}

extern "C" void kernel_launch(void* const* d_in, const int* in_sizes, int n_in,
                              void* d_out, int out_size, void* d_ws, size_t ws_size,
                              hipStream_t stream) {
    const float* in   = (const float*)d_in[0];
    // d_in[1] = lap_rows: rows are repeat(arange(V), DEG) by construction -> implicit
    const int*   cols = (const int*)d_in[2];
    const float* vals = (const float*)d_in[3];
    const float* W    = (const float*)d_in[4];
    const float* bias = (const float*)d_in[5];
    float* out  = (float*)d_out;

    float* bufA = (float*)d_ws;                       // 42 MB
    float* bufB = bufA + (size_t)V_ * D_;             // 42 MB

    dim3 grid(V_), block(256);
    // k=1: x1 = L x0 -> bufB ; out = bias + W0·x0 + W1·x1
    cheb_step<1, true,  true ><<<grid, block, 0, stream>>>(in, in,   in,   bufB, cols, vals, W, bias, out);
    // k=2: x2 = 2 L x1 - x0 -> bufA ; out += W2·x2
    cheb_step<2, false, true ><<<grid, block, 0, stream>>>(in, bufB, in,   bufA, cols, vals, W, bias, out);
    // k=3: x3 = 2 L x2 - x1 -> bufB (in-place over x1: row v touched only by block v) ; out += W3·x3
    cheb_step<3, false, true ><<<grid, block, 0, stream>>>(in, bufA, bufB, bufB, cols, vals, W, bias, out);
    // k=4: x4 = 2 L x3 - x2 (not stored) ; out += W4·x4
    cheb_step<4, false, false><<<grid, block, 0, stream>>>(in, bufB, bufA, bufA, cols, vals, W, bias, out);
}